// Round 10
// baseline (180.699 us; speedup 1.0000x reference)
//
#include <hip/hip_runtime.h>
#include <hip/hip_bf16.h>
#include <stdint.h>

// Fastfood 2D conv, MI355X. fp32 I/O:
// input (16,256,32,32), B/G/S (1,4096), bias (512), P (4096) i32 -> out (16,512,32,32).
// Per pixel: patch j=kk*256+ch (2304, pad 4096), *B, FWHT4096, perm P, *G, FWHT4096,
// *S[0:512]+bias.
//
// R4..R9: pixel quads packed 4-per-uint2-slot, fp16-native pipeline, truncated
//   second FWHT (thread t owns oc=t, 256+t), register-accumulated outputs +
//   one coalesced block-end epilogue. R10 (MFMA, reverted): spilled.
// R11: tap hoisting (24 uint2 in regs; staging buffer dead afterwards).
// R12: OCCUPANCY 2 -> 4 blocks/CU. R11 was neutral despite fewer barriers/LDS ops
//   -> limiter is concurrent drain stalls at 2 blocks/CU (VALU 34%, LDS ~35%,
//   Occ 17%: no pipe >40%). Fix: (a) split each (b,oh) into 2 HALF-blocks of
//   4 quads -> grid 1024; (b) LDS 80 -> 32 KB: staging goes THROUGH the exchange
//   buffer in 2 chunks (kh01 -> hoist -> kh2 -> hoist), since taps live in
//   registers; single buffer, 4 barriers/quad (gather-WAR re-added, ~free per
//   R11). (c) p-loop still unrolled over all 8 bodies with uniform guard
//   (qq>>2)==h -> tap indices stay compile-time (no scratch). (d) co-XCD
//   half-pairing (half = (idx>>3)&1): paired halves write complementary 16B
//   chunks of the same 128B output lines on the same XCD ~concurrently ->
//   lines merge fully-dirty in L2 (WRITE_SIZE is the falsifier), and input
//   fetch is shared in L2.
// LDS: 32 KiB -> 5 blocks/CU cap, 4 resident (grid-limited).

typedef _Float16 h2 __attribute__((ext_vector_type(2)));

__device__ __forceinline__ uint16_t f2h16(float f) {
    union { _Float16 h; uint16_t u; } c; c.h = (_Float16)f; return c.u;
}
__device__ __forceinline__ int swz(int j) {
    return j ^ ((j >> 5) & 7) ^ (((j >> 8) & 1) * 24) ^ (((j >> 9) & 1) * 8);
}
__device__ __forceinline__ uint32_t h2u(h2 v) {
    union { h2 h; uint32_t u; } c; c.h = v; return c.u;
}
__device__ __forceinline__ h2 u2h(uint32_t x) {
    union { h2 h; uint32_t u; } c; c.u = x; return c.h;
}
__device__ __forceinline__ h2 pkh(float a, float b) {
    h2 r; r.x = (_Float16)a; r.y = (_Float16)b; return r;
}
__device__ __forceinline__ void h16h(h2* x) {
    #pragma unroll
    for (int h = 1; h < 16; h <<= 1) {
        #pragma unroll
        for (int g = 0; g < 16; g += 2 * h) {
            #pragma unroll
            for (int u = g; u < g + h; ++u) {
                h2 a = x[u], b = x[u + h];
                x[u]     = a + b;   // -> v_pk_add_f16
                x[u + h] = a - b;
            }
        }
    }
}
// truncated stride-256 round: s = sum_r x[r], d = sum_r (-1)^r x[r]
__device__ __forceinline__ void trunc16(const h2* x, h2& s, h2& d) {
    h2 sp[8], sm[8];
    #pragma unroll
    for (int i = 0; i < 8; ++i) {
        sp[i] = x[2 * i] + x[2 * i + 1];
        sm[i] = x[2 * i] - x[2 * i + 1];
    }
    #pragma unroll
    for (int h = 4; h >= 1; h >>= 1) {
        #pragma unroll
        for (int i = 0; i < h; ++i) { sp[i] = sp[i] + sp[i + h]; sm[i] = sm[i] + sm[i + h]; }
    }
    s = sp[0]; d = sm[0];
}
// slot k of a quad's packed output pair: k=0->ow p, 1->p+8, 2->p+16, 3->p+24.
__device__ __forceinline__ _Float16 slotk(const uint2& u, int k) {
    const h2 a = u2h(u.x), c = u2h(u.y);
    return (k == 0) ? a.x : (k == 1) ? c.x : (k == 2) ? a.y : c.y;
}

__global__ __launch_bounds__(256, 4)
void fastfood_kernel(const float* __restrict__ in,
                     const float* __restrict__ Bm,
                     const float* __restrict__ Gm,
                     const float* __restrict__ Sm,
                     const float* __restrict__ bias,
                     const int* __restrict__ P,
                     float* __restrict__ out)
{
    // Single 32 KiB buffer: staging chunks (as u16), then the b64 exchange, then
    // the epilogue staging.
    __shared__ __align__(16) uint2 bufX[4096];
    uint16_t* s16 = reinterpret_cast<uint16_t*>(bufX);

    const int t  = threadIdx.x;
    const int t1 = t >> 4, t0 = t & 15;
    // co-XCD half pairing: idx and idx+8 share (b,oh), same XCD under %8 RR.
    const int idx = blockIdx.x;
    const int h   = (idx >> 3) & 1;                  // pixel half: p in [4h, 4h+4)
    const int rid = ((idx >> 4) << 3) | (idx & 7);   // (b,oh) row id in [0,512)
    const int b   = rid >> 5, oh = rid & 31;

    // ---- constants (pure global loads; no LDS dependency)
    float Bf[9];
    #pragma unroll
    for (int r = 0; r < 9; ++r) Bf[r] = Bm[r * 256 + t];
    h2 Bh[9];
    #pragma unroll
    for (int r = 0; r < 9; ++r) Bh[r] = pkh(Bf[r], Bf[r]);
    h2 Gh[16]; int PAv[16];
    #pragma unroll
    for (int q = 0; q < 4; ++q) {
        const int4   pv = *reinterpret_cast<const int4*>(P + 16 * t + 4 * q);
        const float4 gv = *reinterpret_cast<const float4*>(Gm + 16 * t + 4 * q);
        PAv[4 * q + 0] = swz(pv.x); PAv[4 * q + 1] = swz(pv.y);
        PAv[4 * q + 2] = swz(pv.z); PAv[4 * q + 3] = swz(pv.w);
        Gh[4 * q + 0] = pkh(gv.x, gv.x); Gh[4 * q + 1] = pkh(gv.y, gv.y);
        Gh[4 * q + 2] = pkh(gv.z, gv.z); Gh[4 * q + 3] = pkh(gv.w, gv.w);
    }

    // ---- staged-through-bufX input: [khc][iwm(8)][ch(256)] uint2
    //      = {h2(v_g, v_g+16), h2(v_g+8, v_g+24)}; khc = ihrel&1 (chunked).
    uint2 tap[3][8];
    #pragma unroll
    for (int i = 0; i < 16; ++i) {               // chunk 1: kh = 0,1 (32 KiB)
        const int idx2  = t + i * 256;
        const int part  = idx2 & 7;
        const int ch    = (idx2 >> 3) & 255;
        const int ihrel = idx2 >> 11;            // 0 or 1
        const int ih    = oh - 1 + ihrel;
        float4 ld = make_float4(0.f, 0.f, 0.f, 0.f);
        if ((unsigned)ih < 32u) {
            ld = *reinterpret_cast<const float4*>(
                in + ((((size_t)b * 256 + ch) * 32 + ih) * 32 + part * 4));
        }
        const int qd   = part >> 1;
        const int slot = (qd == 0) ? 0 : (qd == 1) ? 2 : (qd == 2) ? 1 : 3;
        const int g0   = 4 * (part & 1);
        const int base = ((ihrel * 8 + g0) << 10) + ch * 4 + slot;
        s16[base       ] = f2h16(ld.x);
        s16[base + 1024] = f2h16(ld.y);
        s16[base + 2048] = f2h16(ld.z);
        s16[base + 3072] = f2h16(ld.w);
    }
    __syncthreads();
    #pragma unroll
    for (int kh = 0; kh < 2; ++kh)
        #pragma unroll
        for (int g = 0; g < 8; ++g)
            tap[kh][g] = bufX[(kh * 8 + g) * 256 + t];
    __syncthreads();                              // WAR: hoists done before restage
    #pragma unroll
    for (int i = 16; i < 24; ++i) {               // chunk 2: kh = 2 (16 KiB)
        const int idx2  = t + i * 256;
        const int part  = idx2 & 7;
        const int ch    = (idx2 >> 3) & 255;
        const int ih    = oh + 1;                 // ihrel = 2
        float4 ld = make_float4(0.f, 0.f, 0.f, 0.f);
        if ((unsigned)ih < 32u) {
            ld = *reinterpret_cast<const float4*>(
                in + ((((size_t)b * 256 + ch) * 32 + ih) * 32 + part * 4));
        }
        const int qd   = part >> 1;
        const int slot = (qd == 0) ? 0 : (qd == 1) ? 2 : (qd == 2) ? 1 : 3;
        const int g0   = 4 * (part & 1);
        const int base = ((g0) << 10) + ch * 4 + slot;   // khc = 0
        s16[base       ] = f2h16(ld.x);
        s16[base + 1024] = f2h16(ld.y);
        s16[base + 2048] = f2h16(ld.z);
        s16[base + 3072] = f2h16(ld.w);
    }
    __syncthreads();
    #pragma unroll
    for (int g = 0; g < 8; ++g)
        tap[2][g] = bufX[g * 256 + t];
    __syncthreads();                              // WAR: before first exchange write

    uint2 os[4], od[4];                           // this half's 4 quads (registers)

    #pragma unroll
    for (int qq = 0; qq < 8; ++qq) {
        if ((qq >> 2) != h) continue;             // uniform compile-time-guarded body
        const int p = qq, q = qq & 3;             // quad: ow = p, p+8, p+16, p+24
        h2 x0[16], x1[16];                        // x0=(p, p+16), x1=(p+8, p+24)
        #pragma unroll
        for (int r = 0; r < 9; ++r) {
            const int kh = r / 3, kw = r % 3;
            const int iw = p - 1 + kw;            // compile-time in [-1, 8]
            const uint2 u = tap[kh][iw & 7];      // static index
            h2 a = u2h(u.x), c = u2h(u.y);        // a=(v_g, v_g+16), c=(v_g+8, v_g+24)
            h2 ta = a, tc = c;
            if (iw < 0) {                         // p=0,kw=0: x0=(0,v15), x1=(v7,v23)
                ta.x = (_Float16)0.f; ta.y = c.x;
                tc = a;
            } else if (iw > 7) {                  // p=7,kw=2: x0=(v8,v24), x1=(v16,0)
                ta = c;
                tc.x = a.y; tc.y = (_Float16)0.f;
            }
            x0[r] = Bh[r] * ta;                   // -> v_pk_mul_f16
            x1[r] = Bh[r] * tc;
        }
        #pragma unroll
        for (int r = 9; r < 16; ++r) {
            x0[r] = pkh(0.f, 0.f);
            x1[r] = pkh(0.f, 0.f);
        }

        // ===== pass 0: A(str256) -> B(str16) -> C(str1), stage for gather
        h16h(x0); h16h(x1);                       // round A
        #pragma unroll                            // own slots (prev quad's last reads
        for (int r = 0; r < 16; ++r)              // were these same own slots)
            bufX[swz(256 * r + t)] = make_uint2(h2u(x0[r]), h2u(x1[r]));
        __syncthreads();                          // S1: RAW (A -> B, cross-wave)
        #pragma unroll
        for (int r = 0; r < 16; ++r) {
            const uint2 u = bufX[swz(256 * t1 + 16 * r + t0)];
            x0[r] = u2h(u.x); x1[r] = u2h(u.y);
        }
        h16h(x0); h16h(x1);                       // round B
        #pragma unroll                            // own slots
        for (int r = 0; r < 16; ++r)
            bufX[swz(256 * t1 + 16 * r + t0)] = make_uint2(h2u(x0[r]), h2u(x1[r]));
        // NO barrier: B->C stays within group t1 = 16 contiguous threads (one wave).
        #pragma unroll
        for (int r = 0; r < 16; ++r) {
            const uint2 u = bufX[swz(256 * t1 + 16 * t0 + r)];
            x0[r] = u2h(u.x); x1[r] = u2h(u.y);
        }
        h16h(x0); h16h(x1);                       // round C
        #pragma unroll                            // own slots (stage for gather)
        for (int r = 0; r < 16; ++r)
            bufX[swz(256 * t1 + 16 * t0 + r)] = make_uint2(h2u(x0[r]), h2u(x1[r]));
        __syncthreads();                          // S2: RAW (before perm gather)

        // ===== permutation + G: gather INTO C-layout (thread t owns j = 16t+r)
        #pragma unroll
        for (int r = 0; r < 16; ++r) {
            const uint2 u = bufX[PAv[r]];
            x0[r] = Gh[r] * u2h(u.x);
            x1[r] = Gh[r] * u2h(u.y);
        }

        // ===== pass 1: C(str1) -> B(str16) -> A(str256, truncated)
        h16h(x0); h16h(x1);                       // round C'
        __syncthreads();                          // S2b: WAR (all gathers done)
        #pragma unroll
        for (int r = 0; r < 16; ++r)
            bufX[swz(256 * t1 + 16 * t0 + r)] = make_uint2(h2u(x0[r]), h2u(x1[r]));
        // NO barrier: C'->B' intra-wave (group t1).
        #pragma unroll
        for (int r = 0; r < 16; ++r) {
            const uint2 u = bufX[swz(256 * t1 + 16 * r + t0)];
            x0[r] = u2h(u.x); x1[r] = u2h(u.y);
        }
        h16h(x0); h16h(x1);                       // round B'
        #pragma unroll                            // own slots
        for (int r = 0; r < 16; ++r)
            bufX[swz(256 * t1 + 16 * r + t0)] = make_uint2(h2u(x0[r]), h2u(x1[r]));
        __syncthreads();                          // S3: RAW (B' -> A-layout read)
        #pragma unroll
        for (int r = 0; r < 16; ++r) {            // A-layout: x[r] = j = 256r + t
            const uint2 u = bufX[swz(256 * r + t)];
            x0[r] = u2h(u.x); x1[r] = u2h(u.y);
        }
        // truncated round A: oc = t (sum), oc = 256+t (alternating sum)
        h2 s0, d0, s1, d1;
        trunc16(x0, s0, d0);                      // (ow p, p+16)
        trunc16(x1, s1, d1);                      // (ow p+8, p+24)
        os[q] = make_uint2(h2u(s0), h2u(s1));     // static index -> registers
        od[q] = make_uint2(h2u(d0), h2u(d1));
    }

    // ===== block-end epilogue =====
    // U[ii]/V[ii]: 4 cols (4*(2ii+h) .. +3) of rows oc=t / oc=256+t.
    // col w = 4h + e + 8*ii -> quad q=e slot ii.
    uint2 U[4], V[4];
    #pragma unroll
    for (int ii = 0; ii < 4; ++ii) {
        h2 lo, hi;
        lo.x = slotk(os[0], ii); lo.y = slotk(os[1], ii);
        hi.x = slotk(os[2], ii); hi.y = slotk(os[3], ii);
        U[ii] = make_uint2(h2u(lo), h2u(hi));
        lo.x = slotk(od[0], ii); lo.y = slotk(od[1], ii);
        hi.x = slotk(od[2], ii); hi.y = slotk(od[3], ii);
        V[ii] = make_uint2(h2u(lo), h2u(hi));
    }

    __syncthreads();                              // WAR: quad A-reads done everywhere
    {
        const int sw = (t >> 2) & 3;              // == ((oc>>2)&3) for oc=t and 256+t
        #pragma unroll
        for (int ii = 0; ii < 4; ++ii) {
            bufX[t * 4 + (ii ^ sw)]           = U[ii];
            bufX[(256 + t) * 4 + (ii ^ sw)]   = V[ii];
        }
    }
    __syncthreads();                              // RAW
    // Cooperative store: 8 iters; 16B chunks at cols {4h, 8+4h, 16+4h, 24+4h}.
    #pragma unroll
    for (int it = 0; it < 8; ++it) {
        const int oc = it * 64 + (t >> 2);
        const int ii = t & 3;
        const uint2 u = bufX[oc * 4 + (ii ^ ((oc >> 2) & 3))];
        const h2 lo = u2h(u.x), hi = u2h(u.y);
        const float S = Sm[oc], C = bias[oc];
        const float4 v = make_float4(S * (float)lo.x + C, S * (float)lo.y + C,
                                     S * (float)hi.x + C, S * (float)hi.y + C);
        *reinterpret_cast<float4*>(
            out + ((size_t)b * 512 + oc) * 1024 + (size_t)oh * 32
                + 4 * (2 * ii + h)) = v;
    }
}

extern "C" void kernel_launch(void* const* d_in, const int* in_sizes, int n_in,
                              void* d_out, int out_size, void* d_ws, size_t ws_size,
                              hipStream_t stream) {
    const float* in   = (const float*)d_in[0];
    const float* Bm   = (const float*)d_in[1];
    const float* Gm   = (const float*)d_in[2];
    const float* Sm   = (const float*)d_in[3];
    const float* bias = (const float*)d_in[4];
    const int*   P    = (const int*)d_in[5];
    float* out = (float*)d_out;
    (void)d_ws; (void)ws_size;

    dim3 grid(1024), block(256);
    fastfood_kernel<<<grid, block, 0, stream>>>(in, Bm, Gm, Sm, bias, P, out);
}

// Round 11
// 137.406 us; speedup vs baseline: 1.3151x; 1.3151x over previous
//
#include <hip/hip_runtime.h>
#include <hip/hip_bf16.h>
#include <stdint.h>

// Fastfood 2D conv, MI355X. fp32 I/O:
// input (16,256,32,32), B/G/S (1,4096), bias (512), P (4096) i32 -> out (16,512,32,32).
// Per pixel: patch j=kk*256+ch (2304, pad 4096), *B, FWHT4096, perm P, *G, FWHT4096,
// *S[0:512]+bias.
//
// R4..R9: pixel quads packed 4-per-uint2-slot, fp16-native pipeline, truncated
//   second FWHT (thread t owns oc=t, 256+t), register-accumulated outputs +
//   one coalesced block-end epilogue. R10 (MFMA, reverted): spilled.
// R11: tap hoisting (24 uint2 in regs; staging buffer dead afterwards).
// R12: occupancy 2 -> 4 blocks/CU via (a) HALF-blocks (4 quads each, grid 1024),
//   (b) LDS 80 -> 32 KB (staging chunked THROUGH the exchange buffer),
//   (c) compile-time-guarded unrolled p-loop, (d) co-XCD half-pairing so paired
//   halves merge complementary 16B chunks of the same 128B output lines in L2.
//   FAILED via self-inflicted spill: __launch_bounds__(256,4) forced VGPR=64
//   (kernel needs ~96-150) -> 200+MB scratch traffic. Occupancy itself hit 44%.
// R13: R12 with __launch_bounds__(256,2) — let the compiler take its natural
//   ~96 VGPR (every no-spill round sat at 88-96). Occupancy then bounded by
//   LDS (5 blocks/CU) and grid (4/CU), not a forced register cap.
// LDS: 32 KiB single buffer.

typedef _Float16 h2 __attribute__((ext_vector_type(2)));

__device__ __forceinline__ uint16_t f2h16(float f) {
    union { _Float16 h; uint16_t u; } c; c.h = (_Float16)f; return c.u;
}
__device__ __forceinline__ int swz(int j) {
    return j ^ ((j >> 5) & 7) ^ (((j >> 8) & 1) * 24) ^ (((j >> 9) & 1) * 8);
}
__device__ __forceinline__ uint32_t h2u(h2 v) {
    union { h2 h; uint32_t u; } c; c.h = v; return c.u;
}
__device__ __forceinline__ h2 u2h(uint32_t x) {
    union { h2 h; uint32_t u; } c; c.u = x; return c.h;
}
__device__ __forceinline__ h2 pkh(float a, float b) {
    h2 r; r.x = (_Float16)a; r.y = (_Float16)b; return r;
}
__device__ __forceinline__ void h16h(h2* x) {
    #pragma unroll
    for (int h = 1; h < 16; h <<= 1) {
        #pragma unroll
        for (int g = 0; g < 16; g += 2 * h) {
            #pragma unroll
            for (int u = g; u < g + h; ++u) {
                h2 a = x[u], b = x[u + h];
                x[u]     = a + b;   // -> v_pk_add_f16
                x[u + h] = a - b;
            }
        }
    }
}
// truncated stride-256 round: s = sum_r x[r], d = sum_r (-1)^r x[r]
__device__ __forceinline__ void trunc16(const h2* x, h2& s, h2& d) {
    h2 sp[8], sm[8];
    #pragma unroll
    for (int i = 0; i < 8; ++i) {
        sp[i] = x[2 * i] + x[2 * i + 1];
        sm[i] = x[2 * i] - x[2 * i + 1];
    }
    #pragma unroll
    for (int h = 4; h >= 1; h >>= 1) {
        #pragma unroll
        for (int i = 0; i < h; ++i) { sp[i] = sp[i] + sp[i + h]; sm[i] = sm[i] + sm[i + h]; }
    }
    s = sp[0]; d = sm[0];
}
// slot k of a quad's packed output pair: k=0->ow p, 1->p+8, 2->p+16, 3->p+24.
__device__ __forceinline__ _Float16 slotk(const uint2& u, int k) {
    const h2 a = u2h(u.x), c = u2h(u.y);
    return (k == 0) ? a.x : (k == 1) ? c.x : (k == 2) ? a.y : c.y;
}

__global__ __launch_bounds__(256, 2)
void fastfood_kernel(const float* __restrict__ in,
                     const float* __restrict__ Bm,
                     const float* __restrict__ Gm,
                     const float* __restrict__ Sm,
                     const float* __restrict__ bias,
                     const int* __restrict__ P,
                     float* __restrict__ out)
{
    // Single 32 KiB buffer: staging chunks (as u16), then the b64 exchange, then
    // the epilogue staging.
    __shared__ __align__(16) uint2 bufX[4096];
    uint16_t* s16 = reinterpret_cast<uint16_t*>(bufX);

    const int t  = threadIdx.x;
    const int t1 = t >> 4, t0 = t & 15;
    // co-XCD half pairing: idx and idx+8 share (b,oh), same XCD under %8 RR.
    const int idx = blockIdx.x;
    const int h   = (idx >> 3) & 1;                  // pixel half: p in [4h, 4h+4)
    const int rid = ((idx >> 4) << 3) | (idx & 7);   // (b,oh) row id in [0,512)
    const int b   = rid >> 5, oh = rid & 31;

    // ---- constants (pure global loads; no LDS dependency)
    float Bf[9];
    #pragma unroll
    for (int r = 0; r < 9; ++r) Bf[r] = Bm[r * 256 + t];
    h2 Bh[9];
    #pragma unroll
    for (int r = 0; r < 9; ++r) Bh[r] = pkh(Bf[r], Bf[r]);
    h2 Gh[16]; int PAv[16];
    #pragma unroll
    for (int q = 0; q < 4; ++q) {
        const int4   pv = *reinterpret_cast<const int4*>(P + 16 * t + 4 * q);
        const float4 gv = *reinterpret_cast<const float4*>(Gm + 16 * t + 4 * q);
        PAv[4 * q + 0] = swz(pv.x); PAv[4 * q + 1] = swz(pv.y);
        PAv[4 * q + 2] = swz(pv.z); PAv[4 * q + 3] = swz(pv.w);
        Gh[4 * q + 0] = pkh(gv.x, gv.x); Gh[4 * q + 1] = pkh(gv.y, gv.y);
        Gh[4 * q + 2] = pkh(gv.z, gv.z); Gh[4 * q + 3] = pkh(gv.w, gv.w);
    }

    // ---- staged-through-bufX input: [khc][iwm(8)][ch(256)] uint2
    //      = {h2(v_g, v_g+16), h2(v_g+8, v_g+24)}; khc = ihrel&1 (chunked).
    uint2 tap[3][8];
    #pragma unroll
    for (int i = 0; i < 16; ++i) {               // chunk 1: kh = 0,1 (32 KiB)
        const int idx2  = t + i * 256;
        const int part  = idx2 & 7;
        const int ch    = (idx2 >> 3) & 255;
        const int ihrel = idx2 >> 11;            // 0 or 1
        const int ih    = oh - 1 + ihrel;
        float4 ld = make_float4(0.f, 0.f, 0.f, 0.f);
        if ((unsigned)ih < 32u) {
            ld = *reinterpret_cast<const float4*>(
                in + ((((size_t)b * 256 + ch) * 32 + ih) * 32 + part * 4));
        }
        const int qd   = part >> 1;
        const int slot = (qd == 0) ? 0 : (qd == 1) ? 2 : (qd == 2) ? 1 : 3;
        const int g0   = 4 * (part & 1);
        const int base = ((ihrel * 8 + g0) << 10) + ch * 4 + slot;
        s16[base       ] = f2h16(ld.x);
        s16[base + 1024] = f2h16(ld.y);
        s16[base + 2048] = f2h16(ld.z);
        s16[base + 3072] = f2h16(ld.w);
    }
    __syncthreads();
    #pragma unroll
    for (int kh = 0; kh < 2; ++kh)
        #pragma unroll
        for (int g = 0; g < 8; ++g)
            tap[kh][g] = bufX[(kh * 8 + g) * 256 + t];
    __syncthreads();                              // WAR: hoists done before restage
    #pragma unroll
    for (int i = 16; i < 24; ++i) {               // chunk 2: kh = 2 (16 KiB)
        const int idx2  = t + i * 256;
        const int part  = idx2 & 7;
        const int ch    = (idx2 >> 3) & 255;
        const int ih    = oh + 1;                 // ihrel = 2
        float4 ld = make_float4(0.f, 0.f, 0.f, 0.f);
        if ((unsigned)ih < 32u) {
            ld = *reinterpret_cast<const float4*>(
                in + ((((size_t)b * 256 + ch) * 32 + ih) * 32 + part * 4));
        }
        const int qd   = part >> 1;
        const int slot = (qd == 0) ? 0 : (qd == 1) ? 2 : (qd == 2) ? 1 : 3;
        const int g0   = 4 * (part & 1);
        const int base = ((g0) << 10) + ch * 4 + slot;   // khc = 0
        s16[base       ] = f2h16(ld.x);
        s16[base + 1024] = f2h16(ld.y);
        s16[base + 2048] = f2h16(ld.z);
        s16[base + 3072] = f2h16(ld.w);
    }
    __syncthreads();
    #pragma unroll
    for (int g = 0; g < 8; ++g)
        tap[2][g] = bufX[g * 256 + t];
    __syncthreads();                              // WAR: before first exchange write

    uint2 os[4], od[4];                           // this half's 4 quads (registers)

    #pragma unroll
    for (int qq = 0; qq < 8; ++qq) {
        if ((qq >> 2) != h) continue;             // uniform compile-time-guarded body
        const int p = qq, q = qq & 3;             // quad: ow = p, p+8, p+16, p+24
        h2 x0[16], x1[16];                        // x0=(p, p+16), x1=(p+8, p+24)
        #pragma unroll
        for (int r = 0; r < 9; ++r) {
            const int kh = r / 3, kw = r % 3;
            const int iw = p - 1 + kw;            // compile-time in [-1, 8]
            const uint2 u = tap[kh][iw & 7];      // static index
            h2 a = u2h(u.x), c = u2h(u.y);        // a=(v_g, v_g+16), c=(v_g+8, v_g+24)
            h2 ta = a, tc = c;
            if (iw < 0) {                         // p=0,kw=0: x0=(0,v15), x1=(v7,v23)
                ta.x = (_Float16)0.f; ta.y = c.x;
                tc = a;
            } else if (iw > 7) {                  // p=7,kw=2: x0=(v8,v24), x1=(v16,0)
                ta = c;
                tc.x = a.y; tc.y = (_Float16)0.f;
            }
            x0[r] = Bh[r] * ta;                   // -> v_pk_mul_f16
            x1[r] = Bh[r] * tc;
        }
        #pragma unroll
        for (int r = 9; r < 16; ++r) {
            x0[r] = pkh(0.f, 0.f);
            x1[r] = pkh(0.f, 0.f);
        }

        // ===== pass 0: A(str256) -> B(str16) -> C(str1), stage for gather
        h16h(x0); h16h(x1);                       // round A
        #pragma unroll                            // own slots (prev quad's last reads
        for (int r = 0; r < 16; ++r)              // were these same own slots)
            bufX[swz(256 * r + t)] = make_uint2(h2u(x0[r]), h2u(x1[r]));
        __syncthreads();                          // S1: RAW (A -> B, cross-wave)
        #pragma unroll
        for (int r = 0; r < 16; ++r) {
            const uint2 u = bufX[swz(256 * t1 + 16 * r + t0)];
            x0[r] = u2h(u.x); x1[r] = u2h(u.y);
        }
        h16h(x0); h16h(x1);                       // round B
        #pragma unroll                            // own slots
        for (int r = 0; r < 16; ++r)
            bufX[swz(256 * t1 + 16 * r + t0)] = make_uint2(h2u(x0[r]), h2u(x1[r]));
        // NO barrier: B->C stays within group t1 = 16 contiguous threads (one wave).
        #pragma unroll
        for (int r = 0; r < 16; ++r) {
            const uint2 u = bufX[swz(256 * t1 + 16 * t0 + r)];
            x0[r] = u2h(u.x); x1[r] = u2h(u.y);
        }
        h16h(x0); h16h(x1);                       // round C
        #pragma unroll                            // own slots (stage for gather)
        for (int r = 0; r < 16; ++r)
            bufX[swz(256 * t1 + 16 * t0 + r)] = make_uint2(h2u(x0[r]), h2u(x1[r]));
        __syncthreads();                          // S2: RAW (before perm gather)

        // ===== permutation + G: gather INTO C-layout (thread t owns j = 16t+r)
        #pragma unroll
        for (int r = 0; r < 16; ++r) {
            const uint2 u = bufX[PAv[r]];
            x0[r] = Gh[r] * u2h(u.x);
            x1[r] = Gh[r] * u2h(u.y);
        }

        // ===== pass 1: C(str1) -> B(str16) -> A(str256, truncated)
        h16h(x0); h16h(x1);                       // round C'
        __syncthreads();                          // S2b: WAR (all gathers done)
        #pragma unroll
        for (int r = 0; r < 16; ++r)
            bufX[swz(256 * t1 + 16 * t0 + r)] = make_uint2(h2u(x0[r]), h2u(x1[r]));
        // NO barrier: C'->B' intra-wave (group t1).
        #pragma unroll
        for (int r = 0; r < 16; ++r) {
            const uint2 u = bufX[swz(256 * t1 + 16 * r + t0)];
            x0[r] = u2h(u.x); x1[r] = u2h(u.y);
        }
        h16h(x0); h16h(x1);                       // round B'
        #pragma unroll                            // own slots
        for (int r = 0; r < 16; ++r)
            bufX[swz(256 * t1 + 16 * r + t0)] = make_uint2(h2u(x0[r]), h2u(x1[r]));
        __syncthreads();                          // S3: RAW (B' -> A-layout read)
        #pragma unroll
        for (int r = 0; r < 16; ++r) {            // A-layout: x[r] = j = 256r + t
            const uint2 u = bufX[swz(256 * r + t)];
            x0[r] = u2h(u.x); x1[r] = u2h(u.y);
        }
        // truncated round A: oc = t (sum), oc = 256+t (alternating sum)
        h2 s0, d0, s1, d1;
        trunc16(x0, s0, d0);                      // (ow p, p+16)
        trunc16(x1, s1, d1);                      // (ow p+8, p+24)
        os[q] = make_uint2(h2u(s0), h2u(s1));     // static index -> registers
        od[q] = make_uint2(h2u(d0), h2u(d1));
    }

    // ===== block-end epilogue =====
    // U[ii]/V[ii]: 4 cols (8*ii + 4h .. +3) of rows oc=t / oc=256+t.
    uint2 U[4], V[4];
    #pragma unroll
    for (int ii = 0; ii < 4; ++ii) {
        h2 lo, hi;
        lo.x = slotk(os[0], ii); lo.y = slotk(os[1], ii);
        hi.x = slotk(os[2], ii); hi.y = slotk(os[3], ii);
        U[ii] = make_uint2(h2u(lo), h2u(hi));
        lo.x = slotk(od[0], ii); lo.y = slotk(od[1], ii);
        hi.x = slotk(od[2], ii); hi.y = slotk(od[3], ii);
        V[ii] = make_uint2(h2u(lo), h2u(hi));
    }

    __syncthreads();                              // WAR: quad A-reads done everywhere
    {
        const int sw = (t >> 2) & 3;              // == ((oc>>2)&3) for oc=t and 256+t
        #pragma unroll
        for (int ii = 0; ii < 4; ++ii) {
            bufX[t * 4 + (ii ^ sw)]           = U[ii];
            bufX[(256 + t) * 4 + (ii ^ sw)]   = V[ii];
        }
    }
    __syncthreads();                              // RAW
    // Cooperative store: 8 iters; 16B chunks at cols {4h, 8+4h, 16+4h, 24+4h}.
    #pragma unroll
    for (int it = 0; it < 8; ++it) {
        const int oc = it * 64 + (t >> 2);
        const int ii = t & 3;
        const uint2 u = bufX[oc * 4 + (ii ^ ((oc >> 2) & 3))];
        const h2 lo = u2h(u.x), hi = u2h(u.y);
        const float S = Sm[oc], C = bias[oc];
        const float4 v = make_float4(S * (float)lo.x + C, S * (float)lo.y + C,
                                     S * (float)hi.x + C, S * (float)hi.y + C);
        *reinterpret_cast<float4*>(
            out + ((size_t)b * 512 + oc) * 1024 + (size_t)oh * 32
                + 4 * (2 * ii + h)) = v;
    }
}

extern "C" void kernel_launch(void* const* d_in, const int* in_sizes, int n_in,
                              void* d_out, int out_size, void* d_ws, size_t ws_size,
                              hipStream_t stream) {
    const float* in   = (const float*)d_in[0];
    const float* Bm   = (const float*)d_in[1];
    const float* Gm   = (const float*)d_in[2];
    const float* Sm   = (const float*)d_in[3];
    const float* bias = (const float*)d_in[4];
    const int*   P    = (const int*)d_in[5];
    float* out = (float*)d_out;
    (void)d_ws; (void)ws_size;

    dim3 grid(1024), block(256);
    fastfood_kernel<<<grid, block, 0, stream>>>(in, Bm, Gm, Sm, bias, P, out);
}